// Round 2
// baseline (5515.600 us; speedup 1.0000x reference)
//
#include <hip/hip_runtime.h>
#include <math.h>

// ---------------- problem constants ----------------
constexpr int S_    = 4096;
constexpr int NKV   = 2048;
constexpr int NAUX  = 512;
constexpr int NNEW  = 1536;
constexpr int H_    = 2048;
constexpr int NH_   = 16;
constexpr int HD_   = 128;
constexpr int FF_   = 8192;
constexpr int NQ_   = 2048;   // NNEW + NAUX
constexpr int NK_   = 4096;   // NKV + NQ
constexpr int PRUNE = 409;
constexpr float EPSF = 1e-6f;

// ---------------- index prep ----------------
__global__ __launch_bounds__(256) void prep_build(
    const int* __restrict__ kv_idxs, const int* __restrict__ aux_idxs,
    const int* __restrict__ new_idxs, const int* __restrict__ positions,
    int* hs_idxs, int* q_pos, int* key_tok, int* k_pos,
    int* map_full, int* in_hs, int* aux_bit, int* pruned_bit, int* last_hs)
{
  int t = blockIdx.x * 256 + threadIdx.x;     // grid covers 4096
  if (t < S_) { map_full[t] = 0; in_hs[t] = 0; aux_bit[t] = 0; pruned_bit[t] = 0; }
  if (t < NQ_) {
    int tok = (t < NNEW) ? new_idxs[t] : aux_idxs[t - NNEW];
    hs_idxs[t] = tok;
    q_pos[t] = positions[tok];
  }
  if (t < NK_) {
    int tok;
    if (t < NKV) tok = kv_idxs[t];
    else { int i = t - NKV; tok = (i < NNEW) ? new_idxs[i] : aux_idxs[i - NNEW]; }
    key_tok[t] = tok;
    k_pos[t] = positions[tok];
  }
  if (t < NNEW && new_idxs[t] == S_ - 1) last_hs[0] = t;
}

__global__ __launch_bounds__(256) void prep_scatter(
    const int* __restrict__ hs_idxs, const int* __restrict__ aux_idxs,
    int* map_full, int* in_hs, int* aux_bit)
{
  int t = blockIdx.x * 256 + threadIdx.x;
  if (t < NQ_) { int tok = hs_idxs[t]; map_full[tok] = t; in_hs[tok] = 1; }
  else if (t < NQ_ + NAUX) { aux_bit[aux_idxs[t - NQ_]] = 1; }
}

// Prune semantics of the reference (bug-compatible):
//   jnp.take(attn, last_key, axis=2) is OOB on axis size NQ -> default mode
//   "fill" -> imp = all-NaN; imp.at[last_key].set(inf); top_k(-imp, 409) with
//   IEEE totalOrder (-NaN < -Inf < ... ), ties by ascending index
//   -> prune_list = {last_key} U {0..407}
//   -> to_prune_tok = {S-1} U kv_idxs[0:408]
__global__ __launch_bounds__(256) void prune_set(
    const int* __restrict__ kv_idxs, int* __restrict__ pruned_bit)
{
  int t = blockIdx.x * 256 + threadIdx.x;
  if (t < PRUNE - 1) pruned_bit[kv_idxs[t]] = 1;
  if (t == PRUNE - 1) pruned_bit[S_ - 1] = 1;
}

// ---------------- hs = concat(hidden_states, aux_cache[aux_idxs]) ----------------
__global__ __launch_bounds__(256) void build_hs(
    const float* __restrict__ hidden, const float* __restrict__ auxc,
    const int* __restrict__ aux_idxs, float* __restrict__ hs)
{
  int gid = blockIdx.x * 256 + threadIdx.x;   // NQ*H/4 float4
  int c4 = gid & 511;                          // H/4 = 512
  int i  = gid >> 9;
  const float4* src;
  if (i < NNEW) src = (const float4*)hidden + (size_t)i * 512 + c4;
  else          src = (const float4*)auxc + (size_t)aux_idxs[i - NNEW] * 512 + c4;
  ((float4*)hs)[gid] = *src;
}

// ---------------- rmsnorm ----------------
__global__ __launch_bounds__(256) void rmsnorm_k(
    const float* __restrict__ in, const float* __restrict__ w, float* __restrict__ out)
{
  int row = blockIdx.x, t = threadIdx.x;
  const float4* r4 = (const float4*)(in + (size_t)row * H_);
  const float4* w4 = (const float4*)w;
  float ss = 0.f;
  float4 v0 = r4[t], v1 = r4[t + 256];
  ss += v0.x*v0.x + v0.y*v0.y + v0.z*v0.z + v0.w*v0.w;
  ss += v1.x*v1.x + v1.y*v1.y + v1.z*v1.z + v1.w*v1.w;
  __shared__ float red[256];
  red[t] = ss; __syncthreads();
  for (int s = 128; s > 0; s >>= 1) { if (t < s) red[t] += red[t + s]; __syncthreads(); }
  float inv = rsqrtf(red[0] / (float)H_ + EPSF);
  float4* o4 = (float4*)(out + (size_t)row * H_);
  float4 wv0 = w4[t], wv1 = w4[t + 256];
  float4 r0, r1;
  r0.x = v0.x*inv*wv0.x; r0.y = v0.y*inv*wv0.y; r0.z = v0.z*inv*wv0.z; r0.w = v0.w*inv*wv0.w;
  r1.x = v1.x*inv*wv1.x; r1.y = v1.y*inv*wv1.y; r1.z = v1.z*inv*wv1.z; r1.w = v1.w*inv*wv1.w;
  o4[t] = r0; o4[t + 256] = r1;
}

// ---------------- f32 GEMM: C[M,N] = A[M,K] @ B[K,N] (+epilogue) ----------------
// epi: 0 plain, 1 C = X + acc, 2 C = silu(X) * acc   (X may alias C for epi 2)
__global__ __launch_bounds__(256) void gemm128(
    const float* __restrict__ A, const float* __restrict__ B,
    float* C, const float* X, int M, int N, int K, int epi)
{
  __shared__ float As[16][132];
  __shared__ float Bs[16][132];
  const int bm = blockIdx.y * 128, bn = blockIdx.x * 128;
  const int t = threadIdx.x;
  const int tr = t >> 4, tc = t & 15;
  float acc[8][8];
  #pragma unroll
  for (int j = 0; j < 8; ++j)
    #pragma unroll
    for (int i = 0; i < 8; ++i) acc[j][i] = 0.f;

  for (int k0 = 0; k0 < K; k0 += 16) {
    #pragma unroll
    for (int r = 0; r < 2; ++r) {
      int idx = t + 256 * r;              // 512 float4 of A tile (128x16)
      int arow = idx >> 2;
      int ac = (idx & 3) * 4;
      float4 av = *(const float4*)(A + (size_t)(bm + arow) * K + k0 + ac);
      As[ac + 0][arow] = av.x; As[ac + 1][arow] = av.y;
      As[ac + 2][arow] = av.z; As[ac + 3][arow] = av.w;
    }
    #pragma unroll
    for (int r = 0; r < 2; ++r) {
      int idx = t + 256 * r;              // 512 float4 of B tile (16x128)
      int brow = idx >> 5;
      int bc = (idx & 31) * 4;
      *(float4*)(&Bs[brow][bc]) = *(const float4*)(B + (size_t)(k0 + brow) * N + bn + bc);
    }
    __syncthreads();
    #pragma unroll
    for (int kk = 0; kk < 16; ++kk) {
      float4 a0 = *(const float4*)(&As[kk][tr * 4]);
      float4 a1 = *(const float4*)(&As[kk][64 + tr * 4]);
      float4 b0 = *(const float4*)(&Bs[kk][tc * 4]);
      float4 b1 = *(const float4*)(&Bs[kk][64 + tc * 4]);
      float av[8] = {a0.x,a0.y,a0.z,a0.w,a1.x,a1.y,a1.z,a1.w};
      float bv[8] = {b0.x,b0.y,b0.z,b0.w,b1.x,b1.y,b1.z,b1.w};
      #pragma unroll
      for (int j = 0; j < 8; ++j)
        #pragma unroll
        for (int i = 0; i < 8; ++i) acc[j][i] += av[j] * bv[i];
    }
    __syncthreads();
  }
  #pragma unroll
  for (int j = 0; j < 8; ++j) {
    int row = bm + (j >> 2) * 64 + tr * 4 + (j & 3);
    #pragma unroll
    for (int ci = 0; ci < 2; ++ci) {
      int col = bn + ci * 64 + tc * 4;
      size_t idx = (size_t)row * N + col;
      float4 r;
      r.x = acc[j][ci*4+0]; r.y = acc[j][ci*4+1]; r.z = acc[j][ci*4+2]; r.w = acc[j][ci*4+3];
      if (epi == 1) {
        float4 xv = *(const float4*)(X + idx);
        r.x += xv.x; r.y += xv.y; r.z += xv.z; r.w += xv.w;
      } else if (epi == 2) {
        float4 g = *(const float4*)(X + idx);
        r.x = (g.x / (1.f + expf(-g.x))) * r.x;
        r.y = (g.y / (1.f + expf(-g.y))) * r.y;
        r.z = (g.z / (1.f + expf(-g.z))) * r.z;
        r.w = (g.w / (1.f + expf(-g.w))) * r.w;
      }
      *(float4*)(C + idx) = r;
    }
  }
}

// ---------------- RoPE in-place on q and k (f64 angles: pos amplifies ulp err) ----------------
__global__ __launch_bounds__(256) void rope_k(
    float* __restrict__ qb, float* __restrict__ kb, const int* __restrict__ q_pos)
{
  int gid = blockIdx.x * 256 + threadIdx.x;   // NQ*NH*64
  int d = gid & 63;
  int h = (gid >> 6) & 15;
  int i = gid >> 10;
  int p = q_pos[i];
  // theta^(-d/64) = exp(-d*ln(10000)/64)
  double ang = (double)p * exp((double)d * -0.14391156831212787);
  float c = (float)cos(ang), s = (float)sin(ang);
  size_t ia = (size_t)i * H_ + h * HD_ + d;
  size_t ib = ia + 64;
  float qa = qb[ia], qbv = qb[ib];
  qb[ia] = qa * c - qbv * s;
  qb[ib] = qbv * c + qa * s;
  float ka = kb[ia], kbv = kb[ib];
  kb[ia] = ka * c - kbv * s;
  kb[ib] = kbv * c + ka * s;
}

// ---------------- gather k_all/v_all = [cache rows | new rows], head-major ----------------
__global__ __launch_bounds__(256) void fill_kvall(
    const float* __restrict__ kcache, const float* __restrict__ vcache,
    const float* __restrict__ kb, const float* __restrict__ vb,
    const int* __restrict__ kv_idxs, float* __restrict__ k_all, float* __restrict__ v_all)
{
  int gid = blockIdx.x * 256 + threadIdx.x;   // NH*NK*HD/4
  int d4 = gid & 31;
  int j  = (gid >> 5) & (NK_ - 1);
  int h  = gid >> 17;                          // 32*4096 = 2^17
  float4 kv, vv;
  if (j < NKV) {
    int tok = kv_idxs[j];
    size_t src = ((size_t)h * S_ + tok) * 32 + d4;
    kv = ((const float4*)kcache)[src];
    vv = ((const float4*)vcache)[src];
  } else {
    int i = j - NKV;
    size_t src = (size_t)i * (H_ / 4) + h * 32 + d4;
    kv = ((const float4*)kb)[src];
    vv = ((const float4*)vb)[src];
  }
  ((float4*)k_all)[gid] = kv;
  ((float4*)v_all)[gid] = vv;
}

// ---------------- flash attention (f32), 64 queries x 32-key chunks ----------------
__global__ __launch_bounds__(256) void flash_attn(
    const float* __restrict__ qb, const float* __restrict__ k_all,
    const float* __restrict__ v_all, const int* __restrict__ q_pos,
    const int* __restrict__ k_pos, float* __restrict__ ctx)
{
  const int h = blockIdx.y;
  const int q0 = blockIdx.x * 64;
  __shared__ float qs[64][132];
  __shared__ float ks[32][132];
  __shared__ float vs[32][132];
  __shared__ float sc[64][33];
  __shared__ float mrow[64], lrow[64], arw[64];
  __shared__ int qps[64];
  __shared__ int tile_maxq;
  const int t = threadIdx.x;
  const int tr = t >> 4, tc = t & 15;
  const float scale = 0.08838834764831844f;   // 1/sqrt(128)

  #pragma unroll
  for (int r = 0; r < 8; ++r) {
    int idx = t + 256 * r;                     // 2048 float4 of q tile
    int qi = idx >> 5;
    int c = (idx & 31) * 4;
    *(float4*)(&qs[qi][c]) = *(const float4*)(qb + (size_t)(q0 + qi) * H_ + h * HD_ + c);
  }
  if (t < 64) { mrow[t] = -INFINITY; lrow[t] = 0.f; qps[t] = q_pos[q0 + t]; }
  __syncthreads();
  if (t == 0) {
    int mx = qps[0];
    for (int i = 1; i < 64; ++i) mx = max(mx, qps[i]);
    tile_maxq = mx;
  }
  __syncthreads();

  float acc[4][8];
  #pragma unroll
  for (int j = 0; j < 4; ++j)
    #pragma unroll
    for (int i = 0; i < 8; ++i) acc[j][i] = 0.f;

  for (int kt = 0; kt < NK_ / 32; ++kt) {
    int kbase = kt * 32;
    // positions ascend within each 32-aligned segment chunk: skip fully-masked chunks
    if (k_pos[kbase] > tile_maxq) continue;
    #pragma unroll
    for (int r = 0; r < 4; ++r) {
      int idx = t + 256 * r;                   // 1024 float4 each
      int row = idx >> 5;
      int c = (idx & 31) * 4;
      *(float4*)(&ks[row][c]) = *(const float4*)(k_all + ((size_t)h * NK_ + kbase + row) * HD_ + c);
      *(float4*)(&vs[row][c]) = *(const float4*)(v_all + ((size_t)h * NK_ + kbase + row) * HD_ + c);
    }
    __syncthreads();
    // scores: thread covers queries tr*4+j, keys {tc, tc+16}
    float sv0[4] = {0,0,0,0}, sv1[4] = {0,0,0,0};
    #pragma unroll
    for (int d4 = 0; d4 < 32; ++d4) {
      float4 k0v = *(const float4*)(&ks[tc][d4 * 4]);
      float4 k1v = *(const float4*)(&ks[tc + 16][d4 * 4]);
      #pragma unroll
      for (int j = 0; j < 4; ++j) {
        float4 qv = *(const float4*)(&qs[tr * 4 + j][d4 * 4]);
        sv0[j] += qv.x*k0v.x + qv.y*k0v.y + qv.z*k0v.z + qv.w*k0v.w;
        sv1[j] += qv.x*k1v.x + qv.y*k1v.y + qv.z*k1v.z + qv.w*k1v.w;
      }
    }
    int kp0 = k_pos[kbase + tc], kp1 = k_pos[kbase + tc + 16];
    #pragma unroll
    for (int j = 0; j < 4; ++j) {
      int qp = qps[tr * 4 + j];
      sc[tr * 4 + j][tc]      = (kp0 <= qp) ? sv0[j] * scale : -INFINITY;
      sc[tr * 4 + j][tc + 16] = (kp1 <= qp) ? sv1[j] * scale : -INFINITY;
    }
    __syncthreads();
    if (t < 64) {
      float mo = mrow[t];
      float cm = mo;
      for (int k = 0; k < 32; ++k) cm = fmaxf(cm, sc[t][k]);
      float a = (cm == -INFINITY) ? 1.f : expf(mo - cm);
      float sum = 0.f;
      for (int k = 0; k < 32; ++k) {
        float v = sc[t][k];
        float p = (v == -INFINITY) ? 0.f : expf(v - cm);
        sc[t][k] = p; sum += p;
      }
      mrow[t] = cm; lrow[t] = lrow[t] * a + sum; arw[t] = a;
    }
    __syncthreads();
    #pragma unroll
    for (int j = 0; j < 4; ++j) {
      float a = arw[tr * 4 + j];
      #pragma unroll
      for (int i = 0; i < 8; ++i) acc[j][i] *= a;
    }
    for (int k = 0; k < 32; ++k) {
      float4 v0 = *(const float4*)(&vs[k][tc * 4]);
      float4 v1 = *(const float4*)(&vs[k][64 + tc * 4]);
      #pragma unroll
      for (int j = 0; j < 4; ++j) {
        float p = sc[tr * 4 + j][k];
        acc[j][0] += p*v0.x; acc[j][1] += p*v0.y; acc[j][2] += p*v0.z; acc[j][3] += p*v0.w;
        acc[j][4] += p*v1.x; acc[j][5] += p*v1.y; acc[j][6] += p*v1.z; acc[j][7] += p*v1.w;
      }
    }
    __syncthreads();
  }
  #pragma unroll
  for (int j = 0; j < 4; ++j) {
    int qi = tr * 4 + j;
    float inv = 1.f / lrow[qi];
    float4 o0, o1;
    o0.x = acc[j][0]*inv; o0.y = acc[j][1]*inv; o0.z = acc[j][2]*inv; o0.w = acc[j][3]*inv;
    o1.x = acc[j][4]*inv; o1.y = acc[j][5]*inv; o1.z = acc[j][6]*inv; o1.w = acc[j][7]*inv;
    *(float4*)(ctx + (size_t)(q0 + qi) * H_ + h * HD_ + tc * 4) = o0;
    *(float4*)(ctx + (size_t)(q0 + qi) * H_ + h * HD_ + 64 + tc * 4) = o1;
  }
}

// ---------------- cache scatter outputs ----------------
__global__ __launch_bounds__(256) void write_kv(
    const float* __restrict__ kcache, const float* __restrict__ vcache,
    const float* __restrict__ kb, const float* __restrict__ vb,
    const int* __restrict__ in_hs, const int* __restrict__ map_full,
    float* __restrict__ kc_o, float* __restrict__ vc_o)
{
  int gid = blockIdx.x * 256 + threadIdx.x;   // NH*S*HD/4
  int d4 = gid & 31;
  int s  = (gid >> 5) & (S_ - 1);
  int h  = gid >> 17;
  float4 kv, vv;
  if (in_hs[s]) {
    int i = map_full[s];
    size_t src = (size_t)i * (H_ / 4) + h * 32 + d4;
    kv = ((const float4*)kb)[src];
    vv = ((const float4*)vb)[src];
  } else {
    kv = ((const float4*)kcache)[gid];
    vv = ((const float4*)vcache)[gid];
  }
  ((float4*)kc_o)[gid] = kv;
  ((float4*)vc_o)[gid] = vv;
}

__global__ __launch_bounds__(256) void aux_write(
    const float* __restrict__ outb, const float* __restrict__ auxc,
    const int* __restrict__ pruned_bit, const int* __restrict__ aux_bit,
    const int* __restrict__ map_full, float* __restrict__ aux_o)
{
  int gid = blockIdx.x * 256 + threadIdx.x;   // S*H/4
  int c4 = gid & 511;
  int s  = gid >> 9;
  float4 v;
  if (pruned_bit[s] && !aux_bit[s])
    v = ((const float4*)outb)[(size_t)map_full[s] * 512 + c4];
  else
    v = ((const float4*)auxc)[gid];
  ((float4*)aux_o)[gid] = v;
}

// ---------------- host ----------------
extern "C" void kernel_launch(void* const* d_in, const int* in_sizes, int n_in,
                              void* d_out, int out_size, void* d_ws, size_t ws_size,
                              hipStream_t stream) {
  (void)in_sizes; (void)n_in; (void)out_size; (void)ws_size;
  const float* hidden  = (const float*)d_in[0];
  const float* kcache  = (const float*)d_in[1];
  const float* vcache  = (const float*)d_in[2];
  const float* auxc    = (const float*)d_in[3];
  const int* kv_idxs   = (const int*)d_in[4];
  const int* aux_idxs  = (const int*)d_in[5];
  const int* new_idxs  = (const int*)d_in[6];
  const int* positions = (const int*)d_in[7];
  const float* wq      = (const float*)d_in[8];
  const float* wk      = (const float*)d_in[9];
  const float* wv      = (const float*)d_in[10];
  const float* wo      = (const float*)d_in[11];
  const float* w_gate  = (const float*)d_in[12];
  const float* w_up    = (const float*)d_in[13];
  const float* w_down  = (const float*)d_in[14];
  const float* ln1     = (const float*)d_in[15];
  const float* ln2     = (const float*)d_in[16];

  float* out_o = (float*)d_out;
  float* kc_o  = out_o + (size_t)NQ_ * H_;
  float* vc_o  = kc_o + (size_t)NH_ * S_ * HD_;
  float* aux_o = vc_o + (size_t)NH_ * S_ * HD_;

  // workspace layout (floats); act reuses dead qb/kb/vb/k_all region
  float* W = (float*)d_ws;
  const size_t M4 = 4194304;                  // NQ*H
  float* hs    = W;
  float* x     = W + 1 * M4;                  // also y after attention
  float* qb    = W + 2 * M4;
  float* kb    = W + 3 * M4;
  float* vb    = W + 4 * M4;
  float* k_all = W + 5 * M4;                  // 2*M4
  float* v_all = W + 7 * M4;                  // 2*M4
  float* ctx   = W + 9 * M4;
  float* hs2   = W + 10 * M4;
  float* act   = W + 2 * M4;                  // 4*M4, alias qb..k_all (dead by FFN)
  int* ip = (int*)(W + 11 * M4);
  int* hs_idxs = ip;           ip += NQ_;
  int* q_pos   = ip;           ip += NQ_;
  int* key_tok = ip;           ip += NK_;
  int* k_pos   = ip;           ip += NK_;
  int* map_full= ip;           ip += S_;
  int* in_hs   = ip;           ip += S_;
  int* aux_bit = ip;           ip += S_;
  int* pruned  = ip;           ip += S_;
  int* last_hs = ip;           ip += 4;

  prep_build<<<16, 256, 0, stream>>>(kv_idxs, aux_idxs, new_idxs, positions,
      hs_idxs, q_pos, key_tok, k_pos, map_full, in_hs, aux_bit, pruned, last_hs);
  prep_scatter<<<10, 256, 0, stream>>>(hs_idxs, aux_idxs, map_full, in_hs, aux_bit);
  prune_set<<<2, 256, 0, stream>>>(kv_idxs, pruned);
  build_hs<<<4096, 256, 0, stream>>>(hidden, auxc, aux_idxs, hs);
  rmsnorm_k<<<NQ_, 256, 0, stream>>>(hs, ln1, x);

  gemm128<<<dim3(16, 16), 256, 0, stream>>>(x, wq, qb, nullptr, NQ_, H_, H_, 0);
  gemm128<<<dim3(16, 16), 256, 0, stream>>>(x, wk, kb, nullptr, NQ_, H_, H_, 0);
  gemm128<<<dim3(16, 16), 256, 0, stream>>>(x, wv, vb, nullptr, NQ_, H_, H_, 0);
  rope_k<<<8192, 256, 0, stream>>>(qb, kb, q_pos);
  fill_kvall<<<8192, 256, 0, stream>>>(kcache, vcache, kb, vb, kv_idxs, k_all, v_all);

  flash_attn<<<dim3(32, 16), 256, 0, stream>>>(qb, k_all, v_all, q_pos, k_pos, ctx);
  write_kv<<<8192, 256, 0, stream>>>(kcache, vcache, kb, vb, in_hs, map_full, kc_o, vc_o);

  gemm128<<<dim3(16, 16), 256, 0, stream>>>(ctx, wo, hs2, hs, NQ_, H_, H_, 1);
  rmsnorm_k<<<NQ_, 256, 0, stream>>>(hs2, ln2, x);
  gemm128<<<dim3(64, 16), 256, 0, stream>>>(x, w_gate, act, nullptr, NQ_, FF_, H_, 0);
  gemm128<<<dim3(64, 16), 256, 0, stream>>>(x, w_up, act, act, NQ_, FF_, H_, 2);
  gemm128<<<dim3(16, 16), 256, 0, stream>>>(act, w_down, out_o, hs2, NQ_, H_, FF_, 1);

  aux_write<<<8192, 256, 0, stream>>>(out_o, auxc, pruned, aux_bit, map_full, aux_o);
}